// Round 7
// baseline (494.628 us; speedup 1.0000x reference)
//
#include <hip/hip_runtime.h>

// Batched dynamic-filter cross-correlation:
// x: [128, 384, 384, 1] f32, k: [128, 8, 8, 1] f32
// out[b,i,j] = sum_{p,q} x[b,i+p,j+q] * k[b,p,q], out: [128, 377, 377, 1]
//
// R6 = R1 (the only clean-traffic structure: 32x64 tile, 1x8 strip/thread,
// scalar guarded stores) + z-loop over 8 images per block with register
// double-buffered staging (prefetch next tile during compute).
// Tile/store/compute structure is byte-identical to R1 per iteration.
// (Resubmission: R6 bench was a broker-capacity infra failure, no data.)

#define BATCH 128
#define Hh 384
#define Ww 384
#define KH 8
#define KW 8
#define OH 377
#define OW 377

#define TI 32                 // output tile rows per block
#define TJ 64                 // output tile cols per block
#define XR (TI + KH - 1)      // 39 input rows staged
#define XC4 18                // float4 columns per row (72 floats >= 64+15)
#define XS4 19                // padded LDS row stride in float4 (76 floats)
#define NZ 8                  // images per block

#define NPF 3                 // prefetch float4 per thread: ceil(39*18/256)=3

__global__ __launch_bounds__(256, 3) void corr_kernel(
    const float* __restrict__ x,
    const float* __restrict__ k,
    float* __restrict__ out) {

    __shared__ float4 xs4[XR * XS4];   // 39*19*16 = 11,856 B
    __shared__ float  ks[KH * KW];

    const int tj = blockIdx.x;   // 0..5
    const int ti = blockIdx.y;   // 0..11
    const int zb = blockIdx.z;   // 0..15

    const int bi  = ti * TI;
    const int bj  = tj * TJ;
    const int tid = (int)threadIdx.x;

    // Precompute the (row, col4) slots this thread stages (static unroll).
    int pr[NPF], pc[NPF];
    bool pv[NPF];
#pragma unroll
    for (int j = 0; j < NPF; ++j) {
        const int idx = tid + j * 256;
        pv[j] = (idx < XR * XC4);
        const int r  = idx / XC4;
        const int c4 = idx - r * XC4;
        pr[j] = r;
        pc[j] = c4;
    }

    float4 xreg0, xreg1, xreg2;   // named (rule #20: no runtime-indexed reg arrays)
    float4 kreg;

    // ---- tile loader (global -> regs) for image z ----
    auto load_tile = [&](int z, float4& r0, float4& r1, float4& r2, float4& kr) {
        const float* xb = x + (size_t)z * (Hh * Ww);
        float4 tmp[NPF];
#pragma unroll
        for (int j = 0; j < NPF; ++j) {
            float4 v = make_float4(0.f, 0.f, 0.f, 0.f);
            if (pv[j]) {
                const int grow = bi + pr[j];
                const int gcol = bj + pc[j] * 4;
                if (grow < Hh) {
                    const float* rp = xb + (size_t)grow * Ww + gcol;
                    if (gcol + 3 < Ww) {
                        v = *(const float4*)rp;
                    } else {
                        if (gcol + 0 < Ww) v.x = rp[0];
                        if (gcol + 1 < Ww) v.y = rp[1];
                        if (gcol + 2 < Ww) v.z = rp[2];
                        if (gcol + 3 < Ww) v.w = rp[3];
                    }
                }
            }
            tmp[j] = v;
        }
        r0 = tmp[0]; r1 = tmp[1]; r2 = tmp[2];
        if (tid < 16) {
            kr = ((const float4*)(k + (size_t)z * (KH * KW)))[tid];
        }
    };

    // ---- prologue: prefetch first image ----
    load_tile(zb * NZ, xreg0, xreg1, xreg2, kreg);

    const int txg = tid & 7;     // j-group 0..7
    const int ty  = tid >> 3;    // output row 0..31
    const int j0  = txg * 8;

    for (int zi = 0; zi < NZ; ++zi) {
        const int z = zb * NZ + zi;

        __syncthreads();         // previous iteration's compute done (no-op at zi=0)

        // ---- regs -> LDS ----
        if (pv[0]) xs4[pr[0] * XS4 + pc[0]] = xreg0;
        if (pv[1]) xs4[pr[1] * XS4 + pc[1]] = xreg1;
        if (pv[2]) xs4[pr[2] * XS4 + pc[2]] = xreg2;
        if (tid < 16) ((float4*)ks)[tid] = kreg;

        __syncthreads();         // LDS ready

        // ---- prefetch next image (latency hides under compute below) ----
        if (zi + 1 < NZ) load_tile(z + 1, xreg0, xreg1, xreg2, kreg);

        // ---- compute: each thread one 1x8 output strip (R1 code) ----
        float acc[8];
#pragma unroll
        for (int jj = 0; jj < 8; ++jj) acc[jj] = 0.f;

        const float4* ks4 = (const float4*)ks;

#pragma unroll
        for (int p = 0; p < KH; ++p) {
            float4 k0 = ks4[p * 2 + 0];
            float4 k1 = ks4[p * 2 + 1];
            float kr[8] = {k0.x, k0.y, k0.z, k0.w, k1.x, k1.y, k1.z, k1.w};

            const float4* rowp = &xs4[(ty + p) * XS4 + (j0 >> 2)];
            float4 w0 = rowp[0];
            float4 w1 = rowp[1];
            float4 w2 = rowp[2];
            float4 w3 = rowp[3];
            float xw[16] = {w0.x, w0.y, w0.z, w0.w,
                            w1.x, w1.y, w1.z, w1.w,
                            w2.x, w2.y, w2.z, w2.w,
                            w3.x, w3.y, w3.z, w3.w};

#pragma unroll
            for (int q = 0; q < KW; ++q) {
#pragma unroll
                for (int jj = 0; jj < 8; ++jj) {
                    acc[jj] = fmaf(xw[q + jj], kr[q], acc[jj]);
                }
            }
        }

        // ---- store (R1 idiom, unchanged) ----
        const int oi = bi + ty;
        if (oi < OH) {
            float* ob = out + ((size_t)z * OH + oi) * OW;
#pragma unroll
            for (int jj = 0; jj < 8; ++jj) {
                const int oj = bj + j0 + jj;
                if (oj < OW) ob[oj] = acc[jj];
            }
        }
    }
}

extern "C" void kernel_launch(void* const* d_in, const int* in_sizes, int n_in,
                              void* d_out, int out_size, void* d_ws, size_t ws_size,
                              hipStream_t stream) {
    const float* x = (const float*)d_in[0];
    const float* k = (const float*)d_in[1];
    float* out = (float*)d_out;

    dim3 grid((OW + TJ - 1) / TJ,   // 6
              (OH + TI - 1) / TI,   // 12
              BATCH / NZ);          // 16
    dim3 block(256);
    hipLaunchKernelGGL(corr_kernel, grid, block, 0, stream, x, k, out);
}